// Round 7
// baseline (427.121 us; speedup 1.0000x reference)
//
#include <hip/hip_runtime.h>
#include <math.h>

#define N_NODES 50000
#define N_EDGES 800000

typedef __attribute__((ext_vector_type(8))) short bf16x8;   // 4 VGPRs, MFMA A/B frag
typedef __attribute__((ext_vector_type(4))) float f32x4;    // MFMA C/D frag

__device__ inline unsigned short f2bf(float f) {   // RNE float->bf16
    unsigned u = __float_as_uint(f);
    unsigned r = (u + 0x7fffu + ((u >> 16) & 1u)) >> 16;
    return (unsigned short)r;
}

// ---------------------------------------------------------------------------
// One-time weight prep:
//  W1bf  [128 n][512 k] bf16  (W1^T, K padded 500->512)
//  W2bf  [ 64 n][128 k] bf16  (W2^T)
//  Wcat  [ 80 n][ 64 k] bf16  ([We | W3]^T)
// ---------------------------------------------------------------------------
__global__ __launch_bounds__(256) void convert_weights_kernel(
    const float* __restrict__ W1, const float* __restrict__ W2,
    const float* __restrict__ We, const float* __restrict__ W3,
    unsigned short* __restrict__ W1bf, unsigned short* __restrict__ W2bf,
    unsigned short* __restrict__ Wcat)
{
    int t = blockIdx.x * 256 + threadIdx.x;
    if (t < 65536) {                     // W1bf
        int n = t >> 9, k = t & 511;
        float v = (k < 500) ? W1[k * 128 + n] : 0.0f;
        W1bf[t] = f2bf(v);
    } else if (t < 65536 + 8192) {       // W2bf
        int t2 = t - 65536;
        int n = t2 >> 7, k = t2 & 127;
        W2bf[t2] = f2bf(W2[k * 64 + n]);
    } else if (t < 65536 + 8192 + 5120) { // Wcat
        int t3 = t - 65536 - 8192;
        int n = t3 >> 6, k = t3 & 63;
        float v = (n < 64) ? We[k * 64 + n] : W3[k * 16 + (n - 64)];
        Wcat[t3] = f2bf(v);
    }
}

// ---------------------------------------------------------------------------
// Barrier-free MFMA GEMM1: C[M,128] = A[M,500] @ W1, bf16 out.
// One wave per 16 rows x 64 cols (6250 waves). Software-pipelined: step s+1's
// A (2x float4) and 4 B-frags prefetched into registers before step s's MFMAs,
// so the pre-MFMA waitcnt drains only the older loads (vmcnt(N)-style overlap).
// ---------------------------------------------------------------------------
__global__ __launch_bounds__(256) void gemm1_mfma_kernel(
    const float* __restrict__ A,            // [M,500] fp32
    const unsigned short* __restrict__ Bt,  // [128,512] bf16
    unsigned short* __restrict__ C)         // [M,128] bf16
{
    const int gwid = (blockIdx.x * 256 + threadIdx.x) >> 6;
    const int lane = threadIdx.x & 63;
    const int r = lane & 15, q = lane >> 4;
    const int row0 = (gwid >> 1) * 16;      // 3125 row groups (50000/16 exact)
    const int col0 = (gwid & 1) * 64;       // 2 col halves
    if (row0 >= N_NODES) return;
    const int arow = row0 + r;
    const float* ap = A + (size_t)arow * 500 + q * 8;
    const unsigned short* bp = Bt + (size_t)(col0 + r) * 512 + q * 8;

    const f32x4 zero = {0.0f, 0.0f, 0.0f, 0.0f};
    f32x4 acc[4];
#pragma unroll
    for (int j = 0; j < 4; ++j) acc[j] = zero;

    float4 a0, a1;
    bf16x8 bf[4];

    auto loadA = [&](int s, float4& x0, float4& x1) {
        const int kb = s * 32 + q * 8;
        x0 = make_float4(0.f, 0.f, 0.f, 0.f);
        x1 = make_float4(0.f, 0.f, 0.f, 0.f);
        if (kb < 500)     x0 = *reinterpret_cast<const float4*>(ap + s * 32);
        if (kb + 4 < 500) x1 = *reinterpret_cast<const float4*>(ap + s * 32 + 4);
    };
    auto loadB = [&](int s, bf16x8* d) {
#pragma unroll
        for (int j = 0; j < 4; ++j)
            d[j] = *reinterpret_cast<const bf16x8*>(bp + (size_t)j * 16 * 512 + s * 32);
    };

    loadA(0, a0, a1);
    loadB(0, bf);

    for (int s = 0; s < 16; ++s) {
        // prefetch step s+1 (issues loads; results not needed until next iter)
        float4 na0, na1;
        bf16x8 nb[4];
        if (s < 15) {
            loadA(s + 1, na0, na1);
            loadB(s + 1, nb);
        }
        // convert current A to bf16 and run MFMAs on current frags
        unsigned short h[8] = {f2bf(a0.x), f2bf(a0.y), f2bf(a0.z), f2bf(a0.w),
                               f2bf(a1.x), f2bf(a1.y), f2bf(a1.z), f2bf(a1.w)};
        bf16x8 af = *reinterpret_cast<bf16x8*>(h);
#pragma unroll
        for (int j = 0; j < 4; ++j)
            acc[j] = __builtin_amdgcn_mfma_f32_16x16x32_bf16(af, bf[j], acc[j], 0, 0, 0);
        a0 = na0; a1 = na1;
#pragma unroll
        for (int j = 0; j < 4; ++j) bf[j] = nb[j];
    }

    // D layout: col = lane&15 = r, row = q*4 + reg
#pragma unroll
    for (int reg = 0; reg < 4; ++reg) {
        const int grow = row0 + q * 4 + reg;
#pragma unroll
        for (int j = 0; j < 4; ++j)
            C[(size_t)grow * 128 + col0 + j * 16 + r] = f2bf(acc[j][reg]);
    }
}

// ---------------------------------------------------------------------------
// Barrier-free MFMA GEMM2: sup2[M,64] = h1[M,128](bf16) @ W2, bf16 out.
// ---------------------------------------------------------------------------
__global__ __launch_bounds__(256) void gemm2_mfma_kernel(
    const unsigned short* __restrict__ A,   // [M,128] bf16
    const unsigned short* __restrict__ Bt,  // [64,128] bf16
    unsigned short* __restrict__ C)         // [M,64] bf16
{
    const int wid  = (blockIdx.x * 256 + threadIdx.x) >> 6;
    const int lane = threadIdx.x & 63;
    const int r = lane & 15, q = lane >> 4;
    const int row0 = wid * 16;
    const int arow = row0 + r;
    const bool valid = arow < N_NODES;
    const unsigned short* ap = A + (size_t)arow * 128 + q * 8;

    const f32x4 zero = {0.0f, 0.0f, 0.0f, 0.0f};
    f32x4 acc[4];
#pragma unroll
    for (int j = 0; j < 4; ++j) acc[j] = zero;

#pragma unroll
    for (int s = 0; s < 4; ++s) {
        bf16x8 af = {};
        if (valid) af = *reinterpret_cast<const bf16x8*>(ap + s * 32);
#pragma unroll
        for (int j = 0; j < 4; ++j) {
            bf16x8 bfr = *reinterpret_cast<const bf16x8*>(
                Bt + (size_t)(j * 16 + r) * 128 + s * 32 + q * 8);
            acc[j] = __builtin_amdgcn_mfma_f32_16x16x32_bf16(af, bfr, acc[j], 0, 0, 0);
        }
    }

#pragma unroll
    for (int reg = 0; reg < 4; ++reg) {
        int grow = row0 + q * 4 + reg;
        if (grow < N_NODES) {
#pragma unroll
            for (int j = 0; j < 4; ++j)
                C[(size_t)grow * 64 + j * 16 + r] = f2bf(acc[j][reg]);
        }
    }
}

// ---------------------------------------------------------------------------
// Barrier-free MFMA GEMM3 (fused): h2[M,64](bf16) @ [We|W3] ->
//   cols 0..63: out2 = . + be (fp32), cols 64..79: sup3 (fp32, no bias)
// ---------------------------------------------------------------------------
__global__ __launch_bounds__(256) void gemm3_mfma_kernel(
    const unsigned short* __restrict__ A,   // [M,64] bf16
    const unsigned short* __restrict__ Bt,  // [80,64] bf16
    const float* __restrict__ be,
    float* __restrict__ out2,               // [M,64]
    float* __restrict__ sup3)               // [M,16]
{
    const int wid  = (blockIdx.x * 256 + threadIdx.x) >> 6;
    const int lane = threadIdx.x & 63;
    const int r = lane & 15, q = lane >> 4;
    const int row0 = wid * 16;
    const int arow = row0 + r;
    const bool valid = arow < N_NODES;
    const unsigned short* ap = A + (size_t)arow * 64 + q * 8;

    const f32x4 zero = {0.0f, 0.0f, 0.0f, 0.0f};
    f32x4 acc[5];
#pragma unroll
    for (int j = 0; j < 5; ++j) acc[j] = zero;

#pragma unroll
    for (int s = 0; s < 2; ++s) {
        bf16x8 af = {};
        if (valid) af = *reinterpret_cast<const bf16x8*>(ap + s * 32);
#pragma unroll
        for (int j = 0; j < 5; ++j) {
            bf16x8 bfr = *reinterpret_cast<const bf16x8*>(
                Bt + (size_t)(j * 16 + r) * 64 + s * 32 + q * 8);
            acc[j] = __builtin_amdgcn_mfma_f32_16x16x32_bf16(af, bfr, acc[j], 0, 0, 0);
        }
    }

    float bev[4];
#pragma unroll
    for (int j = 0; j < 4; ++j) bev[j] = be[j * 16 + r];

#pragma unroll
    for (int reg = 0; reg < 4; ++reg) {
        int grow = row0 + q * 4 + reg;
        if (grow < N_NODES) {
#pragma unroll
            for (int j = 0; j < 4; ++j)
                out2[(size_t)grow * 64 + j * 16 + r] = acc[j][reg] + bev[j];
            sup3[(size_t)grow * 16 + r] = acc[4][reg];
        }
    }
}

// ---------------------------------------------------------------------------
// CSR build (per launch; reused by all 3 aggregation layers).
// ---------------------------------------------------------------------------
__global__ __launch_bounds__(256) void hist_kernel(
    const int* __restrict__ src, int* __restrict__ counts)
{
    int e = blockIdx.x * 256 + threadIdx.x;
    if (e < N_EDGES) atomicAdd(&counts[src[e]], 1);
}

__global__ __launch_bounds__(1024) void scan_kernel(
    const int* __restrict__ counts, int* __restrict__ row_ptr,
    int* __restrict__ cursor)
{
    constexpr int Q = N_NODES / 4;
    const int t = threadIdx.x;
    const int lane = t & 63, wave = t >> 6;
    __shared__ int wsum[16];
    __shared__ int carry_s;
    int carry = 0;
    const int4* c4 = reinterpret_cast<const int4*>(counts);
    int4* rp4 = reinterpret_cast<int4*>(row_ptr);
    int4* cu4 = reinterpret_cast<int4*>(cursor);

    for (int base = 0; base < Q; base += 1024) {
        const int g = base + t;
        int4 v = {0, 0, 0, 0};
        if (g < Q) v = c4[g];
        const int s = v.x + v.y + v.z + v.w;

        int incl = s;
#pragma unroll
        for (int off = 1; off < 64; off <<= 1) {
            int n = __shfl_up(incl, off, 64);
            if (lane >= off) incl += n;
        }
        if (lane == 63) wsum[wave] = incl;
        __syncthreads();
        if (t < 16) {
            int w = wsum[t];
            int inc = w;
#pragma unroll
            for (int off = 1; off < 16; off <<= 1) {
                int n = __shfl_up(inc, off, 64);
                if (t >= off) inc += n;
            }
            wsum[t] = inc - w;
            if (t == 15) carry_s = inc;
        }
        __syncthreads();
        if (g < Q) {
            int e0 = carry + wsum[wave] + (incl - s);
            int4 r;
            r.x = e0;
            r.y = r.x + v.x;
            r.z = r.y + v.y;
            r.w = r.z + v.z;
            rp4[g] = r;
            cu4[g] = r;
        }
        carry += carry_s;
        __syncthreads();
    }
    if (t == 0) row_ptr[N_NODES] = carry;
}

__global__ __launch_bounds__(256) void fill_kernel(
    const int* __restrict__ src, const int* __restrict__ dst,
    const float* __restrict__ vals, int* __restrict__ cursor,
    int2* __restrict__ pairs)
{
    int e = blockIdx.x * 256 + threadIdx.x;
    if (e >= N_EDGES) return;
    int pos = atomicAdd(&cursor[src[e]], 1);
    pairs[pos] = make_int2(dst[e], __float_as_int(vals[e]));
}

// ---------------------------------------------------------------------------
// CSR gather F=128 bf16 in -> fused (+b1, relu) -> bf16 out. 16 lanes/node.
// ---------------------------------------------------------------------------
__global__ __launch_bounds__(256) void gather128_bf16_kernel(
    const unsigned short* __restrict__ support, const int2* __restrict__ pairs,
    const int* __restrict__ row_ptr, const float* __restrict__ b1,
    unsigned short* __restrict__ h1)
{
    const int node = blockIdx.x * 16 + (threadIdx.x >> 4);
    if (node >= N_NODES) return;
    const int lane = threadIdx.x & 15;
    int i = row_ptr[node];
    const int end = row_ptr[node + 1];

    float acc[8] = {};
    for (; i + 2 <= end; i += 2) {
        int2 p0 = pairs[i], p1 = pairs[i + 1];
        float v0 = __int_as_float(p0.y), v1 = __int_as_float(p1.y);
        uint4 r0 = *reinterpret_cast<const uint4*>(
            support + (size_t)p0.x * 128 + lane * 8);
        uint4 r1 = *reinterpret_cast<const uint4*>(
            support + (size_t)p1.x * 128 + lane * 8);
        unsigned w0[4] = {r0.x, r0.y, r0.z, r0.w};
        unsigned w1[4] = {r1.x, r1.y, r1.z, r1.w};
#pragma unroll
        for (int j = 0; j < 4; ++j) {
            acc[2 * j]     += __uint_as_float(w0[j] << 16) * v0;
            acc[2 * j + 1] += __uint_as_float(w0[j] & 0xffff0000u) * v0;
            acc[2 * j]     += __uint_as_float(w1[j] << 16) * v1;
            acc[2 * j + 1] += __uint_as_float(w1[j] & 0xffff0000u) * v1;
        }
    }
    if (i < end) {
        int2 p = pairs[i];
        float v = __int_as_float(p.y);
        uint4 r = *reinterpret_cast<const uint4*>(
            support + (size_t)p.x * 128 + lane * 8);
        unsigned w[4] = {r.x, r.y, r.z, r.w};
#pragma unroll
        for (int j = 0; j < 4; ++j) {
            acc[2 * j]     += __uint_as_float(w[j] << 16) * v;
            acc[2 * j + 1] += __uint_as_float(w[j] & 0xffff0000u) * v;
        }
    }
    const float4 ba = *reinterpret_cast<const float4*>(b1 + lane * 8);
    const float4 bb = *reinterpret_cast<const float4*>(b1 + lane * 8 + 4);
    float bias[8] = {ba.x, ba.y, ba.z, ba.w, bb.x, bb.y, bb.z, bb.w};
    unsigned short h[8];
#pragma unroll
    for (int j = 0; j < 8; ++j) {
        float v = acc[j] + bias[j];
        h[j] = f2bf(v > 0.0f ? v : 0.0f);
    }
    *reinterpret_cast<uint4*>(h1 + (size_t)node * 128 + lane * 8) =
        *reinterpret_cast<uint4*>(h);
}

// CSR gather F=64 bf16 in -> fused (+b2, relu) -> bf16 out. 8 lanes/node.
__global__ __launch_bounds__(256) void gather64_bf16_kernel(
    const unsigned short* __restrict__ support, const int2* __restrict__ pairs,
    const int* __restrict__ row_ptr, const float* __restrict__ b2,
    unsigned short* __restrict__ h2)
{
    const int node = blockIdx.x * 32 + (threadIdx.x >> 3);
    if (node >= N_NODES) return;
    const int lane = threadIdx.x & 7;
    int i = row_ptr[node];
    const int end = row_ptr[node + 1];

    float acc[8] = {};
    for (; i + 2 <= end; i += 2) {
        int2 p0 = pairs[i], p1 = pairs[i + 1];
        float v0 = __int_as_float(p0.y), v1 = __int_as_float(p1.y);
        uint4 r0 = *reinterpret_cast<const uint4*>(
            support + (size_t)p0.x * 64 + lane * 8);
        uint4 r1 = *reinterpret_cast<const uint4*>(
            support + (size_t)p1.x * 64 + lane * 8);
        unsigned w0[4] = {r0.x, r0.y, r0.z, r0.w};
        unsigned w1[4] = {r1.x, r1.y, r1.z, r1.w};
#pragma unroll
        for (int j = 0; j < 4; ++j) {
            acc[2 * j]     += __uint_as_float(w0[j] << 16) * v0;
            acc[2 * j + 1] += __uint_as_float(w0[j] & 0xffff0000u) * v0;
            acc[2 * j]     += __uint_as_float(w1[j] << 16) * v1;
            acc[2 * j + 1] += __uint_as_float(w1[j] & 0xffff0000u) * v1;
        }
    }
    if (i < end) {
        int2 p = pairs[i];
        float v = __int_as_float(p.y);
        uint4 r = *reinterpret_cast<const uint4*>(
            support + (size_t)p.x * 64 + lane * 8);
        unsigned w[4] = {r.x, r.y, r.z, r.w};
#pragma unroll
        for (int j = 0; j < 4; ++j) {
            acc[2 * j]     += __uint_as_float(w[j] << 16) * v;
            acc[2 * j + 1] += __uint_as_float(w[j] & 0xffff0000u) * v;
        }
    }
    const float4 ba = *reinterpret_cast<const float4*>(b2 + lane * 8);
    const float4 bb = *reinterpret_cast<const float4*>(b2 + lane * 8 + 4);
    float bias[8] = {ba.x, ba.y, ba.z, ba.w, bb.x, bb.y, bb.z, bb.w};
    unsigned short h[8];
#pragma unroll
    for (int j = 0; j < 8; ++j) {
        float v = acc[j] + bias[j];
        h[j] = f2bf(v > 0.0f ? v : 0.0f);
    }
    *reinterpret_cast<uint4*>(h2 + (size_t)node * 64 + lane * 8) =
        *reinterpret_cast<uint4*>(h);
}

// fp32 gather for F=16 (support3 fp32).
__global__ __launch_bounds__(256) void gather16_kernel(
    const float* __restrict__ support, const int2* __restrict__ pairs,
    const int* __restrict__ row_ptr, float* __restrict__ agg)
{
    const int node = blockIdx.x * 64 + (threadIdx.x >> 2);
    if (node >= N_NODES) return;
    const int lane = threadIdx.x & 3;
    int i = row_ptr[node];
    const int end = row_ptr[node + 1];

    float4 acc0 = {0, 0, 0, 0};
    float4 acc1 = {0, 0, 0, 0};

    for (; i + 2 <= end; i += 2) {
        int2 p0 = pairs[i];
        int2 p1 = pairs[i + 1];
        float v0 = __int_as_float(p0.y);
        float v1 = __int_as_float(p1.y);
        const float4 m0 = *reinterpret_cast<const float4*>(
            support + (size_t)p0.x * 16 + lane * 4);
        const float4 m1 = *reinterpret_cast<const float4*>(
            support + (size_t)p1.x * 16 + lane * 4);
        acc0.x += m0.x * v0; acc0.y += m0.y * v0;
        acc0.z += m0.z * v0; acc0.w += m0.w * v0;
        acc1.x += m1.x * v1; acc1.y += m1.y * v1;
        acc1.z += m1.z * v1; acc1.w += m1.w * v1;
    }
    if (i < end) {
        int2 p = pairs[i];
        float v = __int_as_float(p.y);
        const float4 m = *reinterpret_cast<const float4*>(
            support + (size_t)p.x * 16 + lane * 4);
        acc0.x += m.x * v; acc0.y += m.y * v;
        acc0.z += m.z * v; acc0.w += m.w * v;
    }
    acc0.x += acc1.x; acc0.y += acc1.y; acc0.z += acc1.z; acc0.w += acc1.w;
    *reinterpret_cast<float4*>(agg + (size_t)node * 16 + lane * 4) = acc0;
}

// ---------------------------------------------------------------------------
// Row-wise log_softmax over 16 columns (with bias b3).
// ---------------------------------------------------------------------------
__global__ __launch_bounds__(256) void logsoftmax_kernel(
    const float* __restrict__ agg, const float* __restrict__ b3,
    float* __restrict__ out)
{
    int row = blockIdx.x * 256 + threadIdx.x;
    if (row >= N_NODES) return;
    float v[16];
    const float4* p = reinterpret_cast<const float4*>(agg + (size_t)row * 16);
#pragma unroll
    for (int i = 0; i < 4; ++i) {
        float4 q = p[i];
        v[i * 4 + 0] = q.x + b3[i * 4 + 0];
        v[i * 4 + 1] = q.y + b3[i * 4 + 1];
        v[i * 4 + 2] = q.z + b3[i * 4 + 2];
        v[i * 4 + 3] = q.w + b3[i * 4 + 3];
    }
    float mx = v[0];
#pragma unroll
    for (int i = 1; i < 16; ++i) mx = fmaxf(mx, v[i]);
    float s = 0.0f;
#pragma unroll
    for (int i = 0; i < 16; ++i) s += expf(v[i] - mx);
    float lse = mx + logf(s);
    float4* o = reinterpret_cast<float4*>(out + (size_t)row * 16);
#pragma unroll
    for (int i = 0; i < 4; ++i)
        o[i] = make_float4(v[i * 4 + 0] - lse, v[i * 4 + 1] - lse,
                           v[i * 4 + 2] - lse, v[i * 4 + 3] - lse);
}

// ---------------------------------------------------------------------------
extern "C" void kernel_launch(void* const* d_in, const int* in_sizes, int n_in,
                              void* d_out, int out_size, void* d_ws, size_t ws_size,
                              hipStream_t stream)
{
    const float* x         = (const float*)d_in[0];
    const float* edge_vals = (const float*)d_in[1];
    const float* W1 = (const float*)d_in[2];
    const float* b1 = (const float*)d_in[3];
    const float* W2 = (const float*)d_in[4];
    const float* b2 = (const float*)d_in[5];
    const float* W3 = (const float*)d_in[6];
    const float* b3 = (const float*)d_in[7];
    const float* We = (const float*)d_in[8];
    const float* be = (const float*)d_in[9];
    const int* esrc = (const int*)d_in[10];
    const int* edst = (const int*)d_in[11];

    float* out1 = (float*)d_out;                        // [50000,16]
    float* out2 = (float*)d_out + (size_t)N_NODES * 16; // [50000,64]

    char* ws = (char*)d_ws;
    float* bufA    = (float*)(ws);                    // 25,600,000
    float* bufB    = (float*)(ws + 25600000);         // 25,600,000
    float* bufC    = (float*)(ws + 51200000);         //  3,200,000
    int*   counts  = (int*)  (ws + 54400000);         //    200,064
    int*   row_ptr = (int*)  (ws + 54600064);         //    200,064
    int*   cursor  = (int*)  (ws + 54800128);         //    200,064
    int2*  pairs   = (int2*) (ws + 55000192);         //  6,400,000
    // total: 61,400,192 B

    unsigned short* W1bf = (unsigned short*)bufC;                   // 131,072 B
    unsigned short* W2bf = (unsigned short*)((char*)bufC + 131072); //  16,384 B
    unsigned short* Wcat = (unsigned short*)((char*)bufC + 147456); //  10,240 B

    unsigned short* sup1bf = (unsigned short*)bufA;   // [N,128] bf16
    unsigned short* h1bf   = (unsigned short*)bufB;   // [N,128] bf16
    unsigned short* sup2bf = (unsigned short*)bufA;   // [N,64]  bf16
    unsigned short* h2bf   = (unsigned short*)bufB;   // [N,64]  bf16
    float*          sup3   = bufA;                    // [N,16]  fp32
    float*          agg3   = bufC;                    // [N,16]  fp32 (weights done)

    const int WB = (N_NODES / 16 + 3) / 4;  // 782 blocks (gemm2/gemm3: 16 rows/wave)
    const int G1 = (2 * (N_NODES / 16) + 3) / 4;  // 1563 blocks (gemm1: 6250 waves)
    const int EB = (N_EDGES + 255) / 256;   // 3125

    // --- one-time weight prep + CSR build ---
    convert_weights_kernel<<<308, 256, 0, stream>>>(W1, W2, We, W3, W1bf, W2bf, Wcat);
    hipMemsetAsync(counts, 0, (size_t)N_NODES * 4, stream);
    hist_kernel<<<EB, 256, 0, stream>>>(esrc, counts);
    scan_kernel<<<1, 1024, 0, stream>>>(counts, row_ptr, cursor);
    fill_kernel<<<EB, 256, 0, stream>>>(esrc, edst, edge_vals, cursor, pairs);

    // 1. support1 = x @ W1                 (MFMA)     -> bufA [N,128] bf16
    gemm1_mfma_kernel<<<G1, 256, 0, stream>>>(x, W1bf, sup1bf);

    // 2. h1 = relu(gather(support1) + b1)             -> bufB [N,128] bf16
    gather128_bf16_kernel<<<(N_NODES + 15) / 16, 256, 0, stream>>>(
        sup1bf, pairs, row_ptr, b1, h1bf);

    // 3. support2 = h1 @ W2                (MFMA)     -> bufA [N,64] bf16
    gemm2_mfma_kernel<<<WB, 256, 0, stream>>>(h1bf, W2bf, sup2bf);

    // 4. h2 = relu(gather(support2) + b2)             -> bufB [N,64] bf16
    gather64_bf16_kernel<<<(N_NODES + 31) / 32, 256, 0, stream>>>(
        sup2bf, pairs, row_ptr, b2, h2bf);

    // 5+6. [out2 | support3] = h2 @ [We|W3] (MFMA)    -> d_out tail + bufA [N,16]
    gemm3_mfma_kernel<<<WB, 256, 0, stream>>>(h2bf, Wcat, be, out2, sup3);

    // 7. agg3 = gather(support3)                      -> bufC [N,16] fp32
    gather16_kernel<<<(N_NODES + 63) / 64, 256, 0, stream>>>(
        sup3, pairs, row_ptr, agg3);

    // 8. out1 = log_softmax(agg3 + b3)                -> d_out head
    logsoftmax_kernel<<<(N_NODES + 255) / 256, 256, 0, stream>>>(agg3, b3, out1);
}

// Round 8
// 371.132 us; speedup vs baseline: 1.1509x; 1.1509x over previous
//
#include <hip/hip_runtime.h>
#include <hip/hip_bf16.h>
#include <math.h>

#define N_NODES 50000
#define N_EDGES 800000

typedef __attribute__((ext_vector_type(8))) short bf16x8;   // 4 VGPRs, MFMA A/B frag
typedef __attribute__((ext_vector_type(4))) float f32x4;    // MFMA C/D frag

__device__ inline unsigned short f2bf(float f) {   // RNE float->bf16
    unsigned u = __float_as_uint(f);
    unsigned r = (u + 0x7fffu + ((u >> 16) & 1u)) >> 16;
    return (unsigned short)r;
}

// packed RNE f32x8 -> bf16x8 (v_cvt_pk_bf16_f32: 4 instrs instead of ~32)
__device__ inline bf16x8 pack8(float4 a0, float4 a1) {
    union { __hip_bfloat162 h2[4]; bf16x8 v; } u;
    u.h2[0] = __float22bfloat162_rn(make_float2(a0.x, a0.y));
    u.h2[1] = __float22bfloat162_rn(make_float2(a0.z, a0.w));
    u.h2[2] = __float22bfloat162_rn(make_float2(a1.x, a1.y));
    u.h2[3] = __float22bfloat162_rn(make_float2(a1.z, a1.w));
    return u.v;
}

// ---------------------------------------------------------------------------
// One-time weight prep:
//  W1frag [2 h][4 j][16 s][64 lane][8] bf16 — W1^T in MFMA B-fragment order
//          (k = s*32 + (lane>>4)*8 + jj, n = h*64 + j*16 + (lane&15); k>=500 -> 0)
//  W2bf   [64 n][128 k] bf16  (W2^T)
//  Wcat   [80 n][ 64 k] bf16  ([We | W3]^T)
// ---------------------------------------------------------------------------
__global__ __launch_bounds__(256) void convert_weights_kernel(
    const float* __restrict__ W1, const float* __restrict__ W2,
    const float* __restrict__ We, const float* __restrict__ W3,
    unsigned short* __restrict__ W1frag, unsigned short* __restrict__ W2bf,
    unsigned short* __restrict__ Wcat)
{
    int t = blockIdx.x * 256 + threadIdx.x;
    if (t < 65536) {                     // W1frag
        int h = t >> 15;
        int r1 = t & 32767;
        int j = r1 >> 13;
        int r2 = r1 & 8191;
        int s = r2 >> 9;
        int r3 = r2 & 511;
        int lane = r3 >> 3, jj = r3 & 7;
        int k = s * 32 + (lane >> 4) * 8 + jj;
        int n = h * 64 + j * 16 + (lane & 15);
        float v = (k < 500) ? W1[k * 128 + n] : 0.0f;
        W1frag[t] = f2bf(v);
    } else if (t < 65536 + 8192) {       // W2bf
        int t2 = t - 65536;
        int n = t2 >> 7, k = t2 & 127;
        W2bf[t2] = f2bf(W2[k * 64 + n]);
    } else if (t < 65536 + 8192 + 5120) { // Wcat
        int t3 = t - 65536 - 8192;
        int n = t3 >> 6, k = t3 & 63;
        float v = (n < 64) ? We[k * 64 + n] : W3[k * 16 + (n - 64)];
        Wcat[t3] = f2bf(v);
    }
}

// ---------------------------------------------------------------------------
// GEMM1: C[M,128] = A[M,500] @ W1, bf16 out.
// Grid: 512 blocks (2 col-halves x 256). Block: 4 waves, 64 KB LDS holding
// its col-half of W1 in fragment order (loaded once, ONE barrier). Waves then
// stream 16-row chunks barrier-free: per K-step 2 global A-loads (fp32,
// packed-cvt to bf16) + 4 conflict-free ds_read_b128 + 4 MFMAs.
// K tail: A address clamped to 496 (values land on zeroed B rows).
// ---------------------------------------------------------------------------
__global__ __launch_bounds__(256, 2) void gemm1_mfma_kernel(
    const float* __restrict__ A,            // [M,500] fp32
    const unsigned short* __restrict__ W1frag,
    unsigned short* __restrict__ C)         // [M,128] bf16
{
    __shared__ __align__(16) unsigned short Bs[32768];   // 64 KB

    const int t = threadIdx.x;
    const int h  = blockIdx.x & 1;          // col half: cols h*64..h*64+63
    const int br = blockIdx.x >> 1;         // 0..255
    const int lane = t & 63;
    const int wave = t >> 6;
    const int r = lane & 15, q = lane >> 4;

    // one-time LDS fill: 4096 uint4, coalesced
    {
        const uint4* src = reinterpret_cast<const uint4*>(W1frag + h * 32768);
        uint4* dst = reinterpret_cast<uint4*>(Bs);
#pragma unroll
        for (int i = 0; i < 16; ++i)
            dst[t + i * 256] = src[t + i * 256];
    }
    __syncthreads();   // the only barrier

    const int col0 = h * 64;

    for (int c = br * 4 + wave; c < 3125; c += 1024) {   // 16-row chunks
        const float* ap = A + (size_t)(c * 16 + r) * 500;

        f32x4 acc[4];
#pragma unroll
        for (int j = 0; j < 4; ++j) acc[j] = {0.f, 0.f, 0.f, 0.f};

#pragma unroll 4
        for (int s = 0; s < 16; ++s) {
            const int kb = s * 32 + q * 8;
            const int k0 = kb < 496 ? kb : 496;          // clamp: hits zeroed B
            const int k1 = (kb + 4) < 496 ? (kb + 4) : 496;
            float4 a0 = *reinterpret_cast<const float4*>(ap + k0);
            float4 a1 = *reinterpret_cast<const float4*>(ap + k1);
            bf16x8 af = pack8(a0, a1);
#pragma unroll
            for (int j = 0; j < 4; ++j) {
                bf16x8 b = *reinterpret_cast<const bf16x8*>(
                    &Bs[(size_t)((j * 16 + s) * 64 + lane) * 8]);
                acc[j] = __builtin_amdgcn_mfma_f32_16x16x32_bf16(af, b, acc[j], 0, 0, 0);
            }
        }

        // D layout: col = r, row = q*4 + reg
#pragma unroll
        for (int reg = 0; reg < 4; ++reg) {
            const int grow = c * 16 + q * 4 + reg;
#pragma unroll
            for (int j = 0; j < 4; ++j)
                C[(size_t)grow * 128 + col0 + j * 16 + r] = f2bf(acc[j][reg]);
        }
    }
}

// ---------------------------------------------------------------------------
// Barrier-free MFMA GEMM2: sup2[M,64] = h1[M,128](bf16) @ W2, bf16 out.
// ---------------------------------------------------------------------------
__global__ __launch_bounds__(256) void gemm2_mfma_kernel(
    const unsigned short* __restrict__ A,   // [M,128] bf16
    const unsigned short* __restrict__ Bt,  // [64,128] bf16
    unsigned short* __restrict__ C)         // [M,64] bf16
{
    const int wid  = (blockIdx.x * 256 + threadIdx.x) >> 6;
    const int lane = threadIdx.x & 63;
    const int r = lane & 15, q = lane >> 4;
    const int row0 = wid * 16;
    const int arow = row0 + r;
    const bool valid = arow < N_NODES;
    const unsigned short* ap = A + (size_t)arow * 128 + q * 8;

    const f32x4 zero = {0.0f, 0.0f, 0.0f, 0.0f};
    f32x4 acc[4];
#pragma unroll
    for (int j = 0; j < 4; ++j) acc[j] = zero;

#pragma unroll
    for (int s = 0; s < 4; ++s) {
        bf16x8 af = {};
        if (valid) af = *reinterpret_cast<const bf16x8*>(ap + s * 32);
#pragma unroll
        for (int j = 0; j < 4; ++j) {
            bf16x8 bfr = *reinterpret_cast<const bf16x8*>(
                Bt + (size_t)(j * 16 + r) * 128 + s * 32 + q * 8);
            acc[j] = __builtin_amdgcn_mfma_f32_16x16x32_bf16(af, bfr, acc[j], 0, 0, 0);
        }
    }

#pragma unroll
    for (int reg = 0; reg < 4; ++reg) {
        int grow = row0 + q * 4 + reg;
        if (grow < N_NODES) {
#pragma unroll
            for (int j = 0; j < 4; ++j)
                C[(size_t)grow * 64 + j * 16 + r] = f2bf(acc[j][reg]);
        }
    }
}

// ---------------------------------------------------------------------------
// Barrier-free MFMA GEMM3 (fused): h2[M,64](bf16) @ [We|W3] ->
//   cols 0..63: out2 = . + be (fp32), cols 64..79: sup3 (fp32, no bias)
// ---------------------------------------------------------------------------
__global__ __launch_bounds__(256) void gemm3_mfma_kernel(
    const unsigned short* __restrict__ A,   // [M,64] bf16
    const unsigned short* __restrict__ Bt,  // [80,64] bf16
    const float* __restrict__ be,
    float* __restrict__ out2,               // [M,64]
    float* __restrict__ sup3)               // [M,16]
{
    const int wid  = (blockIdx.x * 256 + threadIdx.x) >> 6;
    const int lane = threadIdx.x & 63;
    const int r = lane & 15, q = lane >> 4;
    const int row0 = wid * 16;
    const int arow = row0 + r;
    const bool valid = arow < N_NODES;
    const unsigned short* ap = A + (size_t)arow * 64 + q * 8;

    const f32x4 zero = {0.0f, 0.0f, 0.0f, 0.0f};
    f32x4 acc[5];
#pragma unroll
    for (int j = 0; j < 5; ++j) acc[j] = zero;

#pragma unroll
    for (int s = 0; s < 2; ++s) {
        bf16x8 af = {};
        if (valid) af = *reinterpret_cast<const bf16x8*>(ap + s * 32);
#pragma unroll
        for (int j = 0; j < 5; ++j) {
            bf16x8 bfr = *reinterpret_cast<const bf16x8*>(
                Bt + (size_t)(j * 16 + r) * 64 + s * 32 + q * 8);
            acc[j] = __builtin_amdgcn_mfma_f32_16x16x32_bf16(af, bfr, acc[j], 0, 0, 0);
        }
    }

    float bev[4];
#pragma unroll
    for (int j = 0; j < 4; ++j) bev[j] = be[j * 16 + r];

#pragma unroll
    for (int reg = 0; reg < 4; ++reg) {
        int grow = row0 + q * 4 + reg;
        if (grow < N_NODES) {
#pragma unroll
            for (int j = 0; j < 4; ++j)
                out2[(size_t)grow * 64 + j * 16 + r] = acc[j][reg] + bev[j];
            sup3[(size_t)grow * 16 + r] = acc[4][reg];
        }
    }
}

// ---------------------------------------------------------------------------
// CSR build (per launch; reused by all 3 aggregation layers).
// ---------------------------------------------------------------------------
__global__ __launch_bounds__(256) void hist_kernel(
    const int* __restrict__ src, int* __restrict__ counts)
{
    int e = blockIdx.x * 256 + threadIdx.x;
    if (e < N_EDGES) atomicAdd(&counts[src[e]], 1);
}

__global__ __launch_bounds__(1024) void scan_kernel(
    const int* __restrict__ counts, int* __restrict__ row_ptr,
    int* __restrict__ cursor)
{
    constexpr int Q = N_NODES / 4;
    const int t = threadIdx.x;
    const int lane = t & 63, wave = t >> 6;
    __shared__ int wsum[16];
    __shared__ int carry_s;
    int carry = 0;
    const int4* c4 = reinterpret_cast<const int4*>(counts);
    int4* rp4 = reinterpret_cast<int4*>(row_ptr);
    int4* cu4 = reinterpret_cast<int4*>(cursor);

    for (int base = 0; base < Q; base += 1024) {
        const int g = base + t;
        int4 v = {0, 0, 0, 0};
        if (g < Q) v = c4[g];
        const int s = v.x + v.y + v.z + v.w;

        int incl = s;
#pragma unroll
        for (int off = 1; off < 64; off <<= 1) {
            int n = __shfl_up(incl, off, 64);
            if (lane >= off) incl += n;
        }
        if (lane == 63) wsum[wave] = incl;
        __syncthreads();
        if (t < 16) {
            int w = wsum[t];
            int inc = w;
#pragma unroll
            for (int off = 1; off < 16; off <<= 1) {
                int n = __shfl_up(inc, off, 64);
                if (t >= off) inc += n;
            }
            wsum[t] = inc - w;
            if (t == 15) carry_s = inc;
        }
        __syncthreads();
        if (g < Q) {
            int e0 = carry + wsum[wave] + (incl - s);
            int4 r;
            r.x = e0;
            r.y = r.x + v.x;
            r.z = r.y + v.y;
            r.w = r.z + v.z;
            rp4[g] = r;
            cu4[g] = r;
        }
        carry += carry_s;
        __syncthreads();
    }
    if (t == 0) row_ptr[N_NODES] = carry;
}

__global__ __launch_bounds__(256) void fill_kernel(
    const int* __restrict__ src, const int* __restrict__ dst,
    const float* __restrict__ vals, int* __restrict__ cursor,
    int2* __restrict__ pairs)
{
    int e = blockIdx.x * 256 + threadIdx.x;
    if (e >= N_EDGES) return;
    int pos = atomicAdd(&cursor[src[e]], 1);
    pairs[pos] = make_int2(dst[e], __float_as_int(vals[e]));
}

// ---------------------------------------------------------------------------
// CSR gather F=128 bf16 in -> fused (+b1, relu) -> bf16 out. 16 lanes/node.
// ---------------------------------------------------------------------------
__global__ __launch_bounds__(256) void gather128_bf16_kernel(
    const unsigned short* __restrict__ support, const int2* __restrict__ pairs,
    const int* __restrict__ row_ptr, const float* __restrict__ b1,
    unsigned short* __restrict__ h1)
{
    const int node = blockIdx.x * 16 + (threadIdx.x >> 4);
    if (node >= N_NODES) return;
    const int lane = threadIdx.x & 15;
    int i = row_ptr[node];
    const int end = row_ptr[node + 1];

    float acc[8] = {};
    for (; i + 2 <= end; i += 2) {
        int2 p0 = pairs[i], p1 = pairs[i + 1];
        float v0 = __int_as_float(p0.y), v1 = __int_as_float(p1.y);
        uint4 r0 = *reinterpret_cast<const uint4*>(
            support + (size_t)p0.x * 128 + lane * 8);
        uint4 r1 = *reinterpret_cast<const uint4*>(
            support + (size_t)p1.x * 128 + lane * 8);
        unsigned w0[4] = {r0.x, r0.y, r0.z, r0.w};
        unsigned w1[4] = {r1.x, r1.y, r1.z, r1.w};
#pragma unroll
        for (int j = 0; j < 4; ++j) {
            acc[2 * j]     += __uint_as_float(w0[j] << 16) * v0;
            acc[2 * j + 1] += __uint_as_float(w0[j] & 0xffff0000u) * v0;
            acc[2 * j]     += __uint_as_float(w1[j] << 16) * v1;
            acc[2 * j + 1] += __uint_as_float(w1[j] & 0xffff0000u) * v1;
        }
    }
    if (i < end) {
        int2 p = pairs[i];
        float v = __int_as_float(p.y);
        uint4 r = *reinterpret_cast<const uint4*>(
            support + (size_t)p.x * 128 + lane * 8);
        unsigned w[4] = {r.x, r.y, r.z, r.w};
#pragma unroll
        for (int j = 0; j < 4; ++j) {
            acc[2 * j]     += __uint_as_float(w[j] << 16) * v;
            acc[2 * j + 1] += __uint_as_float(w[j] & 0xffff0000u) * v;
        }
    }
    const float4 ba = *reinterpret_cast<const float4*>(b1 + lane * 8);
    const float4 bb = *reinterpret_cast<const float4*>(b1 + lane * 8 + 4);
    float bias[8] = {ba.x, ba.y, ba.z, ba.w, bb.x, bb.y, bb.z, bb.w};
    unsigned short h[8];
#pragma unroll
    for (int j = 0; j < 8; ++j) {
        float v = acc[j] + bias[j];
        h[j] = f2bf(v > 0.0f ? v : 0.0f);
    }
    *reinterpret_cast<uint4*>(h1 + (size_t)node * 128 + lane * 8) =
        *reinterpret_cast<uint4*>(h);
}

// CSR gather F=64 bf16 in -> fused (+b2, relu) -> bf16 out. 8 lanes/node.
__global__ __launch_bounds__(256) void gather64_bf16_kernel(
    const unsigned short* __restrict__ support, const int2* __restrict__ pairs,
    const int* __restrict__ row_ptr, const float* __restrict__ b2,
    unsigned short* __restrict__ h2)
{
    const int node = blockIdx.x * 32 + (threadIdx.x >> 3);
    if (node >= N_NODES) return;
    const int lane = threadIdx.x & 7;
    int i = row_ptr[node];
    const int end = row_ptr[node + 1];

    float acc[8] = {};
    for (; i + 2 <= end; i += 2) {
        int2 p0 = pairs[i], p1 = pairs[i + 1];
        float v0 = __int_as_float(p0.y), v1 = __int_as_float(p1.y);
        uint4 r0 = *reinterpret_cast<const uint4*>(
            support + (size_t)p0.x * 64 + lane * 8);
        uint4 r1 = *reinterpret_cast<const uint4*>(
            support + (size_t)p1.x * 64 + lane * 8);
        unsigned w0[4] = {r0.x, r0.y, r0.z, r0.w};
        unsigned w1[4] = {r1.x, r1.y, r1.z, r1.w};
#pragma unroll
        for (int j = 0; j < 4; ++j) {
            acc[2 * j]     += __uint_as_float(w0[j] << 16) * v0;
            acc[2 * j + 1] += __uint_as_float(w0[j] & 0xffff0000u) * v0;
            acc[2 * j]     += __uint_as_float(w1[j] << 16) * v1;
            acc[2 * j + 1] += __uint_as_float(w1[j] & 0xffff0000u) * v1;
        }
    }
    if (i < end) {
        int2 p = pairs[i];
        float v = __int_as_float(p.y);
        uint4 r = *reinterpret_cast<const uint4*>(
            support + (size_t)p.x * 64 + lane * 8);
        unsigned w[4] = {r.x, r.y, r.z, r.w};
#pragma unroll
        for (int j = 0; j < 4; ++j) {
            acc[2 * j]     += __uint_as_float(w[j] << 16) * v;
            acc[2 * j + 1] += __uint_as_float(w[j] & 0xffff0000u) * v;
        }
    }
    const float4 ba = *reinterpret_cast<const float4*>(b2 + lane * 8);
    const float4 bb = *reinterpret_cast<const float4*>(b2 + lane * 8 + 4);
    float bias[8] = {ba.x, ba.y, ba.z, ba.w, bb.x, bb.y, bb.z, bb.w};
    unsigned short h[8];
#pragma unroll
    for (int j = 0; j < 8; ++j) {
        float v = acc[j] + bias[j];
        h[j] = f2bf(v > 0.0f ? v : 0.0f);
    }
    *reinterpret_cast<uint4*>(h2 + (size_t)node * 64 + lane * 8) =
        *reinterpret_cast<uint4*>(h);
}

// fp32 gather for F=16 (support3 fp32).
__global__ __launch_bounds__(256) void gather16_kernel(
    const float* __restrict__ support, const int2* __restrict__ pairs,
    const int* __restrict__ row_ptr, float* __restrict__ agg)
{
    const int node = blockIdx.x * 64 + (threadIdx.x >> 2);
    if (node >= N_NODES) return;
    const int lane = threadIdx.x & 3;
    int i = row_ptr[node];
    const int end = row_ptr[node + 1];

    float4 acc0 = {0, 0, 0, 0};
    float4 acc1 = {0, 0, 0, 0};

    for (; i + 2 <= end; i += 2) {
        int2 p0 = pairs[i];
        int2 p1 = pairs[i + 1];
        float v0 = __int_as_float(p0.y);
        float v1 = __int_as_float(p1.y);
        const float4 m0 = *reinterpret_cast<const float4*>(
            support + (size_t)p0.x * 16 + lane * 4);
        const float4 m1 = *reinterpret_cast<const float4*>(
            support + (size_t)p1.x * 16 + lane * 4);
        acc0.x += m0.x * v0; acc0.y += m0.y * v0;
        acc0.z += m0.z * v0; acc0.w += m0.w * v0;
        acc1.x += m1.x * v1; acc1.y += m1.y * v1;
        acc1.z += m1.z * v1; acc1.w += m1.w * v1;
    }
    if (i < end) {
        int2 p = pairs[i];
        float v = __int_as_float(p.y);
        const float4 m = *reinterpret_cast<const float4*>(
            support + (size_t)p.x * 16 + lane * 4);
        acc0.x += m.x * v; acc0.y += m.y * v;
        acc0.z += m.z * v; acc0.w += m.w * v;
    }
    acc0.x += acc1.x; acc0.y += acc1.y; acc0.z += acc1.z; acc0.w += acc1.w;
    *reinterpret_cast<float4*>(agg + (size_t)node * 16 + lane * 4) = acc0;
}

// ---------------------------------------------------------------------------
// Row-wise log_softmax over 16 columns (with bias b3).
// ---------------------------------------------------------------------------
__global__ __launch_bounds__(256) void logsoftmax_kernel(
    const float* __restrict__ agg, const float* __restrict__ b3,
    float* __restrict__ out)
{
    int row = blockIdx.x * 256 + threadIdx.x;
    if (row >= N_NODES) return;
    float v[16];
    const float4* p = reinterpret_cast<const float4*>(agg + (size_t)row * 16);
#pragma unroll
    for (int i = 0; i < 4; ++i) {
        float4 q = p[i];
        v[i * 4 + 0] = q.x + b3[i * 4 + 0];
        v[i * 4 + 1] = q.y + b3[i * 4 + 1];
        v[i * 4 + 2] = q.z + b3[i * 4 + 2];
        v[i * 4 + 3] = q.w + b3[i * 4 + 3];
    }
    float mx = v[0];
#pragma unroll
    for (int i = 1; i < 16; ++i) mx = fmaxf(mx, v[i]);
    float s = 0.0f;
#pragma unroll
    for (int i = 0; i < 16; ++i) s += expf(v[i] - mx);
    float lse = mx + logf(s);
    float4* o = reinterpret_cast<float4*>(out + (size_t)row * 16);
#pragma unroll
    for (int i = 0; i < 4; ++i)
        o[i] = make_float4(v[i * 4 + 0] - lse, v[i * 4 + 1] - lse,
                           v[i * 4 + 2] - lse, v[i * 4 + 3] - lse);
}

// ---------------------------------------------------------------------------
extern "C" void kernel_launch(void* const* d_in, const int* in_sizes, int n_in,
                              void* d_out, int out_size, void* d_ws, size_t ws_size,
                              hipStream_t stream)
{
    const float* x         = (const float*)d_in[0];
    const float* edge_vals = (const float*)d_in[1];
    const float* W1 = (const float*)d_in[2];
    const float* b1 = (const float*)d_in[3];
    const float* W2 = (const float*)d_in[4];
    const float* b2 = (const float*)d_in[5];
    const float* W3 = (const float*)d_in[6];
    const float* b3 = (const float*)d_in[7];
    const float* We = (const float*)d_in[8];
    const float* be = (const float*)d_in[9];
    const int* esrc = (const int*)d_in[10];
    const int* edst = (const int*)d_in[11];

    float* out1 = (float*)d_out;                        // [50000,16]
    float* out2 = (float*)d_out + (size_t)N_NODES * 16; // [50000,64]

    char* ws = (char*)d_ws;
    float* bufA    = (float*)(ws);                    // 25,600,000
    float* bufB    = (float*)(ws + 25600000);         // 25,600,000
    float* bufC    = (float*)(ws + 51200000);         //  3,200,000
    int*   counts  = (int*)  (ws + 54400000);         //    200,064
    int*   row_ptr = (int*)  (ws + 54600064);         //    200,064
    int*   cursor  = (int*)  (ws + 54800128);         //    200,064
    int2*  pairs   = (int2*) (ws + 55000192);         //  6,400,000
    // total: 61,400,192 B

    unsigned short* W1frag = (unsigned short*)bufC;                 // 131,072 B
    unsigned short* W2bf = (unsigned short*)((char*)bufC + 131072); //  16,384 B
    unsigned short* Wcat = (unsigned short*)((char*)bufC + 147456); //  10,240 B

    unsigned short* sup1bf = (unsigned short*)bufA;   // [N,128] bf16
    unsigned short* h1bf   = (unsigned short*)bufB;   // [N,128] bf16
    unsigned short* sup2bf = (unsigned short*)bufA;   // [N,64]  bf16
    unsigned short* h2bf   = (unsigned short*)bufB;   // [N,64]  bf16
    float*          sup3   = bufA;                    // [N,16]  fp32
    float*          agg3   = bufC;                    // [N,16]  fp32 (weights done)

    const int WB = (N_NODES / 16 + 3) / 4;  // 782 blocks (gemm2/gemm3)
    const int EB = (N_EDGES + 255) / 256;   // 3125

    // --- one-time weight prep + CSR build ---
    convert_weights_kernel<<<308, 256, 0, stream>>>(W1, W2, We, W3, W1frag, W2bf, Wcat);
    hipMemsetAsync(counts, 0, (size_t)N_NODES * 4, stream);
    hist_kernel<<<EB, 256, 0, stream>>>(esrc, counts);
    scan_kernel<<<1, 1024, 0, stream>>>(counts, row_ptr, cursor);
    fill_kernel<<<EB, 256, 0, stream>>>(esrc, edst, edge_vals, cursor, pairs);

    // 1. support1 = x @ W1                 (MFMA)     -> bufA [N,128] bf16
    gemm1_mfma_kernel<<<512, 256, 0, stream>>>(x, W1frag, sup1bf);

    // 2. h1 = relu(gather(support1) + b1)             -> bufB [N,128] bf16
    gather128_bf16_kernel<<<(N_NODES + 15) / 16, 256, 0, stream>>>(
        sup1bf, pairs, row_ptr, b1, h1bf);

    // 3. support2 = h1 @ W2                (MFMA)     -> bufA [N,64] bf16
    gemm2_mfma_kernel<<<WB, 256, 0, stream>>>(h1bf, W2bf, sup2bf);

    // 4. h2 = relu(gather(support2) + b2)             -> bufB [N,64] bf16
    gather64_bf16_kernel<<<(N_NODES + 31) / 32, 256, 0, stream>>>(
        sup2bf, pairs, row_ptr, b2, h2bf);

    // 5+6. [out2 | support3] = h2 @ [We|W3] (MFMA)    -> d_out tail + bufA [N,16]
    gemm3_mfma_kernel<<<WB, 256, 0, stream>>>(h2bf, Wcat, be, out2, sup3);

    // 7. agg3 = gather(support3)                      -> bufC [N,16] fp32
    gather16_kernel<<<(N_NODES + 63) / 64, 256, 0, stream>>>(
        sup3, pairs, row_ptr, agg3);

    // 8. out1 = log_softmax(agg3 + b3)                -> d_out head
    logsoftmax_kernel<<<(N_NODES + 255) / 256, 256, 0, stream>>>(agg3, b3, out1);
}

// Round 9
// 370.341 us; speedup vs baseline: 1.1533x; 1.0021x over previous
//
#include <hip/hip_runtime.h>
#include <hip/hip_bf16.h>
#include <math.h>

#define N_NODES 50000
#define N_EDGES 800000

typedef __attribute__((ext_vector_type(8))) short bf16x8;   // 4 VGPRs, MFMA A/B frag
typedef __attribute__((ext_vector_type(4))) float f32x4;    // MFMA C/D frag

__device__ inline unsigned short f2bf(float f) {   // RNE float->bf16
    unsigned u = __float_as_uint(f);
    unsigned r = (u + 0x7fffu + ((u >> 16) & 1u)) >> 16;
    return (unsigned short)r;
}

// packed RNE f32x8 -> bf16x8 (v_cvt_pk_bf16_f32)
__device__ inline bf16x8 pack8(float4 a0, float4 a1) {
    union { __hip_bfloat162 h2[4]; bf16x8 v; } u;
    u.h2[0] = __float22bfloat162_rn(make_float2(a0.x, a0.y));
    u.h2[1] = __float22bfloat162_rn(make_float2(a0.z, a0.w));
    u.h2[2] = __float22bfloat162_rn(make_float2(a1.x, a1.y));
    u.h2[3] = __float22bfloat162_rn(make_float2(a1.z, a1.w));
    return u.v;
}

// ---------------------------------------------------------------------------
// Fused one-time prep + histogram.
// Blocks 0..307: weight conversion into MFMA B-fragment order:
//   W1frag [2 h][4 j][16 s][64 lane][8]  (k=s*32+(lane>>4)*8+jj, n=h*64+j*16+(lane&15))
//   W2frag [4 j][ 4 s][64 lane][8]
//   Wcfrag [5 j][ 2 s][64 lane][8]       ([We | W3] concat on n)
// Blocks 308+: count-histogram of edge_src (counts pre-zeroed by memset).
// ---------------------------------------------------------------------------
__global__ __launch_bounds__(256) void convert_hist_kernel(
    const float* __restrict__ W1, const float* __restrict__ W2,
    const float* __restrict__ We, const float* __restrict__ W3,
    unsigned short* __restrict__ W1frag, unsigned short* __restrict__ W2frag,
    unsigned short* __restrict__ Wcfrag,
    const int* __restrict__ src, int* __restrict__ counts)
{
    if (blockIdx.x < 308) {
        int t = blockIdx.x * 256 + threadIdx.x;   // 0..78847
        if (t < 65536) {                           // W1frag
            int h = t >> 15;
            int r1 = t & 32767;
            int j = r1 >> 13;
            int r2 = r1 & 8191;
            int s = r2 >> 9;
            int r3 = r2 & 511;
            int lane = r3 >> 3, jj = r3 & 7;
            int k = s * 32 + (lane >> 4) * 8 + jj;
            int n = h * 64 + j * 16 + (lane & 15);
            float v = (k < 500) ? W1[k * 128 + n] : 0.0f;
            W1frag[t] = f2bf(v);
        } else if (t < 73728) {                    // W2frag (8192)
            int t2 = t - 65536;
            int j = t2 >> 11;
            int s = (t2 >> 9) & 3;
            int lane = (t2 >> 3) & 63, jj = t2 & 7;
            int k = s * 32 + (lane >> 4) * 8 + jj;
            int n = j * 16 + (lane & 15);
            W2frag[t2] = f2bf(W2[k * 64 + n]);
        } else {                                   // Wcfrag (5120)
            int t3 = t - 73728;
            int j = t3 >> 10;
            int s = (t3 >> 9) & 1;
            int lane = (t3 >> 3) & 63, jj = t3 & 7;
            int k = s * 32 + (lane >> 4) * 8 + jj;
            int n = j * 16 + (lane & 15);
            float v = (n < 64) ? We[k * 64 + n] : W3[k * 16 + (n - 64)];
            Wcfrag[t3] = f2bf(v);
        }
    } else {
        int e = (blockIdx.x - 308) * 256 + threadIdx.x;
        if (e < N_EDGES) atomicAdd(&counts[src[e]], 1);
    }
}

// Single-block coalesced tile scan (int4/thread per tile of 4096).
__global__ __launch_bounds__(1024) void scan_kernel(
    const int* __restrict__ counts, int* __restrict__ row_ptr,
    int* __restrict__ cursor)
{
    constexpr int Q = N_NODES / 4;
    const int t = threadIdx.x;
    const int lane = t & 63, wave = t >> 6;
    __shared__ int wsum[16];
    __shared__ int carry_s;
    int carry = 0;
    const int4* c4 = reinterpret_cast<const int4*>(counts);
    int4* rp4 = reinterpret_cast<int4*>(row_ptr);
    int4* cu4 = reinterpret_cast<int4*>(cursor);

    for (int base = 0; base < Q; base += 1024) {
        const int g = base + t;
        int4 v = {0, 0, 0, 0};
        if (g < Q) v = c4[g];
        const int s = v.x + v.y + v.z + v.w;

        int incl = s;
#pragma unroll
        for (int off = 1; off < 64; off <<= 1) {
            int n = __shfl_up(incl, off, 64);
            if (lane >= off) incl += n;
        }
        if (lane == 63) wsum[wave] = incl;
        __syncthreads();
        if (t < 16) {
            int w = wsum[t];
            int inc = w;
#pragma unroll
            for (int off = 1; off < 16; off <<= 1) {
                int n = __shfl_up(inc, off, 64);
                if (t >= off) inc += n;
            }
            wsum[t] = inc - w;
            if (t == 15) carry_s = inc;
        }
        __syncthreads();
        if (g < Q) {
            int e0 = carry + wsum[wave] + (incl - s);
            int4 r;
            r.x = e0;
            r.y = r.x + v.x;
            r.z = r.y + v.y;
            r.w = r.z + v.z;
            rp4[g] = r;
            cu4[g] = r;
        }
        carry += carry_s;
        __syncthreads();
    }
    if (t == 0) row_ptr[N_NODES] = carry;
}

__global__ __launch_bounds__(256) void fill_kernel(
    const int* __restrict__ src, const int* __restrict__ dst,
    const float* __restrict__ vals, int* __restrict__ cursor,
    int2* __restrict__ pairs)
{
    int e = blockIdx.x * 256 + threadIdx.x;
    if (e >= N_EDGES) return;
    int pos = atomicAdd(&cursor[src[e]], 1);
    pairs[pos] = make_int2(dst[e], __float_as_int(vals[e]));
}

// ---------------------------------------------------------------------------
// GEMM1: C[M,128] = A[M,500] @ W1, bf16 out. (R8 structure — proven.)
// 512 blocks (2 col-halves x 256); 64 KB LDS B-half in fragment order,
// one barrier, then barrier-free 16-row chunks.
// ---------------------------------------------------------------------------
__global__ __launch_bounds__(256, 2) void gemm1_mfma_kernel(
    const float* __restrict__ A,
    const unsigned short* __restrict__ W1frag,
    unsigned short* __restrict__ C)
{
    __shared__ __align__(16) unsigned short Bs[32768];   // 64 KB

    const int t = threadIdx.x;
    const int h  = blockIdx.x & 1;
    const int br = blockIdx.x >> 1;
    const int lane = t & 63;
    const int wave = t >> 6;
    const int r = lane & 15, q = lane >> 4;

    {
        const uint4* src = reinterpret_cast<const uint4*>(W1frag + h * 32768);
        uint4* dst = reinterpret_cast<uint4*>(Bs);
#pragma unroll
        for (int i = 0; i < 16; ++i)
            dst[t + i * 256] = src[t + i * 256];
    }
    __syncthreads();

    const int col0 = h * 64;

    for (int c = br * 4 + wave; c < 3125; c += 1024) {
        const float* ap = A + (size_t)(c * 16 + r) * 500;

        f32x4 acc[4];
#pragma unroll
        for (int j = 0; j < 4; ++j) acc[j] = {0.f, 0.f, 0.f, 0.f};

#pragma unroll 4
        for (int s = 0; s < 16; ++s) {
            const int kb = s * 32 + q * 8;
            const int k0 = kb < 496 ? kb : 496;
            const int k1 = (kb + 4) < 496 ? (kb + 4) : 496;
            float4 a0 = *reinterpret_cast<const float4*>(ap + k0);
            float4 a1 = *reinterpret_cast<const float4*>(ap + k1);
            bf16x8 af = pack8(a0, a1);
#pragma unroll
            for (int j = 0; j < 4; ++j) {
                bf16x8 b = *reinterpret_cast<const bf16x8*>(
                    &Bs[(size_t)((j * 16 + s) * 64 + lane) * 8]);
                acc[j] = __builtin_amdgcn_mfma_f32_16x16x32_bf16(af, b, acc[j], 0, 0, 0);
            }
        }

#pragma unroll
        for (int reg = 0; reg < 4; ++reg) {
            const int grow = c * 16 + q * 4 + reg;
#pragma unroll
            for (int j = 0; j < 4; ++j)
                C[(size_t)grow * 128 + col0 + j * 16 + r] = f2bf(acc[j][reg]);
        }
    }
}

// ---------------------------------------------------------------------------
// GEMM2: sup2[M,64] = h1[M,128](bf16) @ W2, bf16 out. W2 LDS-resident.
// 782 blocks x 4 waves, chunk = 16 rows (3125 chunks exact).
// ---------------------------------------------------------------------------
__global__ __launch_bounds__(256) void gemm2_mfma_kernel(
    const unsigned short* __restrict__ A,
    const unsigned short* __restrict__ W2frag,
    unsigned short* __restrict__ C)
{
    __shared__ __align__(16) unsigned short Bs[8192];   // 16 KB

    const int t = threadIdx.x;
    const int lane = t & 63, wave = t >> 6;
    const int r = lane & 15, q = lane >> 4;

    {
        const uint4* src = reinterpret_cast<const uint4*>(W2frag);
        uint4* dst = reinterpret_cast<uint4*>(Bs);
#pragma unroll
        for (int i = 0; i < 4; ++i)
            dst[t + i * 256] = src[t + i * 256];
    }
    __syncthreads();

    const int c = blockIdx.x * 4 + wave;
    if (c >= 3125) return;
    const unsigned short* ap = A + (size_t)(c * 16 + r) * 128 + q * 8;

    f32x4 acc[4];
#pragma unroll
    for (int j = 0; j < 4; ++j) acc[j] = {0.f, 0.f, 0.f, 0.f};

#pragma unroll
    for (int s = 0; s < 4; ++s) {
        bf16x8 af = *reinterpret_cast<const bf16x8*>(ap + s * 32);
#pragma unroll
        for (int j = 0; j < 4; ++j) {
            bf16x8 b = *reinterpret_cast<const bf16x8*>(
                &Bs[(size_t)((j * 4 + s) * 64 + lane) * 8]);
            acc[j] = __builtin_amdgcn_mfma_f32_16x16x32_bf16(af, b, acc[j], 0, 0, 0);
        }
    }

#pragma unroll
    for (int reg = 0; reg < 4; ++reg) {
        const int grow = c * 16 + q * 4 + reg;
#pragma unroll
        for (int j = 0; j < 4; ++j)
            C[(size_t)grow * 64 + j * 16 + r] = f2bf(acc[j][reg]);
    }
}

// ---------------------------------------------------------------------------
// GEMM3 (fused): h2[M,64](bf16) @ [We|W3] -> out2 (+be, fp32) | sup3 (fp32).
// Wcat LDS-resident. 782 blocks x 4 waves.
// ---------------------------------------------------------------------------
__global__ __launch_bounds__(256) void gemm3_mfma_kernel(
    const unsigned short* __restrict__ A,
    const unsigned short* __restrict__ Wcfrag,
    const float* __restrict__ be,
    float* __restrict__ out2,
    float* __restrict__ sup3)
{
    __shared__ __align__(16) unsigned short Bs[5120];   // 10 KB

    const int t = threadIdx.x;
    const int lane = t & 63, wave = t >> 6;
    const int r = lane & 15, q = lane >> 4;

    {
        const uint4* src = reinterpret_cast<const uint4*>(Wcfrag);
        uint4* dst = reinterpret_cast<uint4*>(Bs);
#pragma unroll
        for (int i = 0; i < 2; ++i)
            dst[t + i * 256] = src[t + i * 256];
        if (t < 128) dst[512 + t] = src[512 + t];
    }
    __syncthreads();

    const int c = blockIdx.x * 4 + wave;
    if (c >= 3125) return;
    const unsigned short* ap = A + (size_t)(c * 16 + r) * 64 + q * 8;

    f32x4 acc[5];
#pragma unroll
    for (int j = 0; j < 5; ++j) acc[j] = {0.f, 0.f, 0.f, 0.f};

#pragma unroll
    for (int s = 0; s < 2; ++s) {
        bf16x8 af = *reinterpret_cast<const bf16x8*>(ap + s * 32);
#pragma unroll
        for (int j = 0; j < 5; ++j) {
            bf16x8 b = *reinterpret_cast<const bf16x8*>(
                &Bs[(size_t)((j * 2 + s) * 64 + lane) * 8]);
            acc[j] = __builtin_amdgcn_mfma_f32_16x16x32_bf16(af, b, acc[j], 0, 0, 0);
        }
    }

    float bev[4];
#pragma unroll
    for (int j = 0; j < 4; ++j) bev[j] = be[j * 16 + r];

#pragma unroll
    for (int reg = 0; reg < 4; ++reg) {
        const int grow = c * 16 + q * 4 + reg;
#pragma unroll
        for (int j = 0; j < 4; ++j)
            out2[(size_t)grow * 64 + j * 16 + r] = acc[j][reg] + bev[j];
        sup3[(size_t)grow * 16 + r] = acc[4][reg];
    }
}

// ---------------------------------------------------------------------------
// Gather F=128, wave-per-node: 16 feat-lanes x 4 edge-slots, shfl_xor reduce.
// Fused +b1, relu, bf16 out. Zero intra-wave divergence (all lanes same node).
// ---------------------------------------------------------------------------
__global__ __launch_bounds__(256) void gather128_kernel(
    const unsigned short* __restrict__ support, const int2* __restrict__ pairs,
    const int* __restrict__ row_ptr, const float* __restrict__ b1,
    unsigned short* __restrict__ h1)
{
    const int node = blockIdx.x * 4 + (threadIdx.x >> 6);
    const int lane = threadIdx.x & 63;
    const int f = lane & 15, e = lane >> 4;
    int i = row_ptr[node] + e;
    const int end = row_ptr[node + 1];

    float acc[8] = {};
    for (; i + 4 < end; i += 8) {
        int2 p0 = pairs[i], p1 = pairs[i + 4];
        float v0 = __int_as_float(p0.y), v1 = __int_as_float(p1.y);
        uint4 r0 = *reinterpret_cast<const uint4*>(support + (size_t)p0.x * 128 + f * 8);
        uint4 r1 = *reinterpret_cast<const uint4*>(support + (size_t)p1.x * 128 + f * 8);
        unsigned w0[4] = {r0.x, r0.y, r0.z, r0.w};
        unsigned w1[4] = {r1.x, r1.y, r1.z, r1.w};
#pragma unroll
        for (int j = 0; j < 4; ++j) {
            acc[2 * j]     += __uint_as_float(w0[j] << 16) * v0;
            acc[2 * j + 1] += __uint_as_float(w0[j] & 0xffff0000u) * v0;
            acc[2 * j]     += __uint_as_float(w1[j] << 16) * v1;
            acc[2 * j + 1] += __uint_as_float(w1[j] & 0xffff0000u) * v1;
        }
    }
    if (i < end) {
        int2 p = pairs[i];
        float v = __int_as_float(p.y);
        uint4 r = *reinterpret_cast<const uint4*>(support + (size_t)p.x * 128 + f * 8);
        unsigned w[4] = {r.x, r.y, r.z, r.w};
#pragma unroll
        for (int j = 0; j < 4; ++j) {
            acc[2 * j]     += __uint_as_float(w[j] << 16) * v;
            acc[2 * j + 1] += __uint_as_float(w[j] & 0xffff0000u) * v;
        }
    }
#pragma unroll
    for (int j = 0; j < 8; ++j) {
        acc[j] += __shfl_xor(acc[j], 16, 64);
        acc[j] += __shfl_xor(acc[j], 32, 64);
    }
    if (e == 0) {
        const float4 ba = *reinterpret_cast<const float4*>(b1 + f * 8);
        const float4 bb = *reinterpret_cast<const float4*>(b1 + f * 8 + 4);
        float bias[8] = {ba.x, ba.y, ba.z, ba.w, bb.x, bb.y, bb.z, bb.w};
        unsigned short h[8];
#pragma unroll
        for (int j = 0; j < 8; ++j) {
            float v = acc[j] + bias[j];
            h[j] = f2bf(v > 0.0f ? v : 0.0f);
        }
        *reinterpret_cast<uint4*>(h1 + (size_t)node * 128 + f * 8) =
            *reinterpret_cast<uint4*>(h);
    }
}

// Gather F=64, wave-per-node: 8 feat-lanes x 8 edge-slots.
__global__ __launch_bounds__(256) void gather64_kernel(
    const unsigned short* __restrict__ support, const int2* __restrict__ pairs,
    const int* __restrict__ row_ptr, const float* __restrict__ b2,
    unsigned short* __restrict__ h2)
{
    const int node = blockIdx.x * 4 + (threadIdx.x >> 6);
    const int lane = threadIdx.x & 63;
    const int f = lane & 7, e = lane >> 3;
    int i = row_ptr[node] + e;
    const int end = row_ptr[node + 1];

    float acc[8] = {};
    for (; i + 8 < end; i += 16) {
        int2 p0 = pairs[i], p1 = pairs[i + 8];
        float v0 = __int_as_float(p0.y), v1 = __int_as_float(p1.y);
        uint4 r0 = *reinterpret_cast<const uint4*>(support + (size_t)p0.x * 64 + f * 8);
        uint4 r1 = *reinterpret_cast<const uint4*>(support + (size_t)p1.x * 64 + f * 8);
        unsigned w0[4] = {r0.x, r0.y, r0.z, r0.w};
        unsigned w1[4] = {r1.x, r1.y, r1.z, r1.w};
#pragma unroll
        for (int j = 0; j < 4; ++j) {
            acc[2 * j]     += __uint_as_float(w0[j] << 16) * v0;
            acc[2 * j + 1] += __uint_as_float(w0[j] & 0xffff0000u) * v0;
            acc[2 * j]     += __uint_as_float(w1[j] << 16) * v1;
            acc[2 * j + 1] += __uint_as_float(w1[j] & 0xffff0000u) * v1;
        }
    }
    if (i < end) {
        int2 p = pairs[i];
        float v = __int_as_float(p.y);
        uint4 r = *reinterpret_cast<const uint4*>(support + (size_t)p.x * 64 + f * 8);
        unsigned w[4] = {r.x, r.y, r.z, r.w};
#pragma unroll
        for (int j = 0; j < 4; ++j) {
            acc[2 * j]     += __uint_as_float(w[j] << 16) * v;
            acc[2 * j + 1] += __uint_as_float(w[j] & 0xffff0000u) * v;
        }
    }
#pragma unroll
    for (int j = 0; j < 8; ++j) {
        acc[j] += __shfl_xor(acc[j], 8, 64);
        acc[j] += __shfl_xor(acc[j], 16, 64);
        acc[j] += __shfl_xor(acc[j], 32, 64);
    }
    if (e == 0) {
        const float4 ba = *reinterpret_cast<const float4*>(b2 + f * 8);
        const float4 bb = *reinterpret_cast<const float4*>(b2 + f * 8 + 4);
        float bias[8] = {ba.x, ba.y, ba.z, ba.w, bb.x, bb.y, bb.z, bb.w};
        unsigned short h[8];
#pragma unroll
        for (int j = 0; j < 8; ++j) {
            float v = acc[j] + bias[j];
            h[j] = f2bf(v > 0.0f ? v : 0.0f);
        }
        *reinterpret_cast<uint4*>(h2 + (size_t)node * 64 + f * 8) =
            *reinterpret_cast<uint4*>(h);
    }
}

// Gather F=16 (fp32) + fused +b3 and log_softmax. 4 feat-lanes x 16 edge-slots.
__global__ __launch_bounds__(256) void gather16_lsm_kernel(
    const float* __restrict__ sup3, const int2* __restrict__ pairs,
    const int* __restrict__ row_ptr, const float* __restrict__ b3,
    float* __restrict__ out1)
{
    const int node = blockIdx.x * 4 + (threadIdx.x >> 6);
    const int lane = threadIdx.x & 63;
    const int f = lane & 3, e = lane >> 2;
    int i = row_ptr[node] + e;
    const int end = row_ptr[node + 1];

    float4 acc = {0, 0, 0, 0};
    for (; i + 16 < end; i += 32) {
        int2 p0 = pairs[i], p1 = pairs[i + 16];
        float v0 = __int_as_float(p0.y), v1 = __int_as_float(p1.y);
        float4 m0 = *reinterpret_cast<const float4*>(sup3 + (size_t)p0.x * 16 + f * 4);
        float4 m1 = *reinterpret_cast<const float4*>(sup3 + (size_t)p1.x * 16 + f * 4);
        acc.x += m0.x * v0 + m1.x * v1;
        acc.y += m0.y * v0 + m1.y * v1;
        acc.z += m0.z * v0 + m1.z * v1;
        acc.w += m0.w * v0 + m1.w * v1;
    }
    if (i < end) {
        int2 p = pairs[i];
        float v = __int_as_float(p.y);
        float4 m = *reinterpret_cast<const float4*>(sup3 + (size_t)p.x * 16 + f * 4);
        acc.x += m.x * v; acc.y += m.y * v; acc.z += m.z * v; acc.w += m.w * v;
    }
    // reduce over 16 edge-slots (xor bits 2..5 of lane)
#pragma unroll
    for (int off = 4; off < 64; off <<= 1) {
        acc.x += __shfl_xor(acc.x, off, 64);
        acc.y += __shfl_xor(acc.y, off, 64);
        acc.z += __shfl_xor(acc.z, off, 64);
        acc.w += __shfl_xor(acc.w, off, 64);
    }
    // lanes 0..3 (e==0) now hold cols f*4..f*4+3; fused log_softmax
    const float4 b = *reinterpret_cast<const float4*>(b3 + f * 4);
    float a0 = acc.x + b.x, a1 = acc.y + b.y, a2 = acc.z + b.z, a3 = acc.w + b.w;
    float mx = fmaxf(fmaxf(a0, a1), fmaxf(a2, a3));
    mx = fmaxf(mx, __shfl_xor(mx, 1, 64));
    mx = fmaxf(mx, __shfl_xor(mx, 2, 64));
    float s = expf(a0 - mx) + expf(a1 - mx) + expf(a2 - mx) + expf(a3 - mx);
    s += __shfl_xor(s, 1, 64);
    s += __shfl_xor(s, 2, 64);
    const float lse = mx + logf(s);
    if (e == 0) {
        float4 o = {a0 - lse, a1 - lse, a2 - lse, a3 - lse};
        *reinterpret_cast<float4*>(out1 + (size_t)node * 16 + f * 4) = o;
    }
}

// ---------------------------------------------------------------------------
extern "C" void kernel_launch(void* const* d_in, const int* in_sizes, int n_in,
                              void* d_out, int out_size, void* d_ws, size_t ws_size,
                              hipStream_t stream)
{
    const float* x         = (const float*)d_in[0];
    const float* edge_vals = (const float*)d_in[1];
    const float* W1 = (const float*)d_in[2];
    const float* b1 = (const float*)d_in[3];
    const float* W2 = (const float*)d_in[4];
    const float* b2 = (const float*)d_in[5];
    const float* W3 = (const float*)d_in[6];
    const float* b3 = (const float*)d_in[7];
    const float* We = (const float*)d_in[8];
    const float* be = (const float*)d_in[9];
    const int* esrc = (const int*)d_in[10];
    const int* edst = (const int*)d_in[11];

    float* out1 = (float*)d_out;                        // [50000,16]
    float* out2 = (float*)d_out + (size_t)N_NODES * 16; // [50000,64]

    char* ws = (char*)d_ws;
    float* bufA    = (float*)(ws);                    // 25,600,000
    float* bufB    = (float*)(ws + 25600000);         // 25,600,000
    float* bufC    = (float*)(ws + 51200000);         //  3,200,000
    int*   counts  = (int*)  (ws + 54400000);         //    200,064
    int*   row_ptr = (int*)  (ws + 54600064);         //    200,064
    int*   cursor  = (int*)  (ws + 54800128);         //    200,064
    int2*  pairs   = (int2*) (ws + 55000192);         //  6,400,000
    // total: 61,400,192 B

    unsigned short* W1frag = (unsigned short*)bufC;                    // 131,072 B
    unsigned short* W2frag = (unsigned short*)((char*)bufC + 131072);  //  16,384 B
    unsigned short* Wcfrag = (unsigned short*)((char*)bufC + 147456);  //  10,240 B

    unsigned short* sup1bf = (unsigned short*)bufA;   // [N,128] bf16
    unsigned short* h1bf   = (unsigned short*)bufB;   // [N,128] bf16
    unsigned short* sup2bf = (unsigned short*)bufA;   // [N,64]  bf16
    unsigned short* h2bf   = (unsigned short*)bufB;   // [N,64]  bf16
    float*          sup3   = bufA;                    // [N,16]  fp32

    const int EB  = (N_EDGES + 255) / 256;  // 3125
    const int GN  = N_NODES / 4;            // 12500 (wave-per-node gathers)
    const int G23 = 782;                    // gemm2/3: 4 waves x 16 rows

    // --- one-time prep + CSR build ---
    hipMemsetAsync(counts, 0, (size_t)N_NODES * 4, stream);
    convert_hist_kernel<<<308 + EB, 256, 0, stream>>>(
        W1, W2, We, W3, W1frag, W2frag, Wcfrag, esrc, counts);
    scan_kernel<<<1, 1024, 0, stream>>>(counts, row_ptr, cursor);
    fill_kernel<<<EB, 256, 0, stream>>>(esrc, edst, edge_vals, cursor, pairs);

    // 1. support1 = x @ W1 (MFMA, LDS-B)            -> bufA [N,128] bf16
    gemm1_mfma_kernel<<<512, 256, 0, stream>>>(x, W1frag, sup1bf);

    // 2. h1 = relu(gather(support1) + b1)           -> bufB [N,128] bf16
    gather128_kernel<<<GN, 256, 0, stream>>>(sup1bf, pairs, row_ptr, b1, h1bf);

    // 3. support2 = h1 @ W2 (MFMA, LDS-B)           -> bufA [N,64] bf16
    gemm2_mfma_kernel<<<G23, 256, 0, stream>>>(h1bf, W2frag, sup2bf);

    // 4. h2 = relu(gather(support2) + b2)           -> bufB [N,64] bf16
    gather64_kernel<<<GN, 256, 0, stream>>>(sup2bf, pairs, row_ptr, b2, h2bf);

    // 5+6. [out2|sup3] = h2 @ [We|W3] (MFMA, LDS-B) -> d_out tail + bufA [N,16]
    gemm3_mfma_kernel<<<G23, 256, 0, stream>>>(h2bf, Wcfrag, be, out2, sup3);

    // 7+8. out1 = log_softmax(gather(sup3) + b3)    -> d_out head
    gather16_lsm_kernel<<<GN, 256, 0, stream>>>(sup3, pairs, row_ptr, b3, out1);
}